// Round 1
// baseline (2069.687 us; speedup 1.0000x reference)
//
#include <hip/hip_runtime.h>
#include <hip/hip_bf16.h>

#define BATCH 2048
#define TSTEPS 32
#define HDIM 1024

typedef __bf16 bf16x8 __attribute__((ext_vector_type(8)));
typedef float f32x4 __attribute__((ext_vector_type(4)));
typedef unsigned short u16;
typedef unsigned int u32;

__device__ __forceinline__ u16 f2bf(float f) {
    u32 u = __float_as_uint(f);
    u = (u + 0x7FFFu + ((u >> 16) & 1u)) >> 16;   // RNE
    return (u16)u;
}
__device__ __forceinline__ float sigf(float x) { return 1.f / (1.f + __expf(-x)); }
__device__ __forceinline__ float tanhfast(float x) { return 1.f - 2.f / (1.f + __expf(2.f * x)); }

// ws layout (bytes):
//  0        : W_bf  (4096*1024 bf16)  8 MB
//  8388608  : h_bf0 (2048*1024 bf16)  4 MB
//  12582912 : h_bf1                   4 MB
//  16777216 : c     (2048*1024 f32)   8 MB
//  25165824 : xtab  (4096 float4)     64 KB

__global__ void k_prep_w(const float* __restrict__ W, u16* __restrict__ Wb) {
    int i = blockIdx.x * 256 + threadIdx.x;           // 1M threads * 4 elems
    float4 v = ((const float4*)W)[i];
    ushort4 o = { f2bf(v.x), f2bf(v.y), f2bf(v.z), f2bf(v.w) };
    ((ushort4*)Wb)[i] = o;
}

__global__ void k_prep_state(const float* __restrict__ h0, const float* __restrict__ c0,
                             u16* __restrict__ hb, float* __restrict__ c) {
    int i = blockIdx.x * 256 + threadIdx.x;           // 512K threads * 4 elems
    float4 v = ((const float4*)h0)[i];
    ushort4 o = { f2bf(v.x), f2bf(v.y), f2bf(v.z), f2bf(v.w) };
    ((ushort4*)hb)[i] = o;
    ((float4*)c)[i] = ((const float4*)c0)[i];
}

__global__ void k_prep_misc(const float* __restrict__ Wih, const float* __restrict__ bih,
                            const float* __restrict__ bhh, float4* __restrict__ xtab) {
    int i = blockIdx.x * 256 + threadIdx.x;           // 4096
    xtab[i] = make_float4(Wih[2 * i], Wih[2 * i + 1], bih[i] + bhh[i], 0.f);
}

__global__ void k_init_out(float* __restrict__ out, const float* __restrict__ fcb) {
    int i = blockIdx.x * 256 + threadIdx.x;           // 65536
    out[i] = fcb[0];
}

// grid (32 colTiles, 8 rowTiles), 512 threads (8 waves).
// Block: 256 batch rows x (32 j x 4 gates). Wave (wr,cg): 64 rows x (16 j x 4 gates).
// Col ordering within block: bc = cg*64 + gate*16 + lr  ->  jg = gate*1024 + jb + cg*16 + lr.
__launch_bounds__(512)
__global__ void k_step(const u16* __restrict__ hin, u16* __restrict__ hout,
                       float* __restrict__ c, const u16* __restrict__ Wb,
                       const float4* __restrict__ xtab, const float* __restrict__ fd,
                       const float* __restrict__ fcW, float* out, int t)
{
    __shared__ uint4 ldsW[1024];   // 128 bc x 8 k8 (16B units), XOR-swizzled

    const int tid  = threadIdx.x;
    const int lane = tid & 63;
    const int wave = tid >> 6;
    const int lr = lane & 15, lk = lane >> 4;
    const int wr = wave >> 1, cg = wave & 1;
    const int colT = blockIdx.x;              // 0..31
    const int rowT = blockIdx.y;              // 0..7
    const int jb   = colT * 32;
    const int mbw  = rowT * 256 + wr * 64;
    const int j    = jb + cg * 16 + lr;       // this lane's hidden column

    // W staging: thread handles 16B units (bc0,k8) and (bc1,k8)
    const int bc0 = tid >> 3, k8 = tid & 7;
    const int bc1 = bc0 + 64;
    const int jg0 = (((bc0 >> 4) & 3) << 10) + jb + ((bc0 >> 6) << 4) + (bc0 & 15);
    const int jg1 = (((bc1 >> 4) & 3) << 10) + jb + ((bc1 >> 6) << 4) + (bc1 & 15);
    const u16* wsrc0 = Wb + jg0 * HDIM + k8 * 8;
    const u16* wsrc1 = Wb + jg1 * HDIM + k8 * 8;
    const int li0 = bc0 * 8 + (k8 ^ (bc0 & 7));
    const int li1 = bc1 * 8 + (k8 ^ (bc1 & 7));

    // A fragment row base (lane reads 8 contiguous k of its row)
    const u16* arow0 = hin + (mbw + lr) * HDIM + lk * 8;
    const int bcf = cg * 64 + lr;

    f32x4 acc[4][4];
#pragma unroll
    for (int a = 0; a < 4; ++a)
#pragma unroll
        for (int b = 0; b < 4; ++b)
            acc[a][b] = (f32x4){0.f, 0.f, 0.f, 0.f};

    uint4 r0 = *(const uint4*)wsrc0;
    uint4 r1 = *(const uint4*)wsrc1;

    for (int kc = 0; kc < 16; ++kc) {
        const int kb = kc * 64;
        __syncthreads();
        ldsW[li0] = r0;
        ldsW[li1] = r1;
        __syncthreads();
        if (kc < 15) {                         // register-prefetch next W chunk
            r0 = *(const uint4*)(wsrc0 + kb + 64);
            r1 = *(const uint4*)(wsrc1 + kb + 64);
        }
#pragma unroll
        for (int ki = 0; ki < 2; ++ki) {
            bf16x8 af0 = *(const bf16x8*)(arow0 + 0 * 16 * HDIM + kb + ki * 32);
            bf16x8 af1 = *(const bf16x8*)(arow0 + 1 * 16 * HDIM + kb + ki * 32);
            bf16x8 af2 = *(const bf16x8*)(arow0 + 2 * 16 * HDIM + kb + ki * 32);
            bf16x8 af3 = *(const bf16x8*)(arow0 + 3 * 16 * HDIM + kb + ki * 32);
#pragma unroll
            for (int cf = 0; cf < 4; ++cf) {
                const int bc = bcf + cf * 16;
                uint4 braw = ldsW[bc * 8 + ((ki * 4 + lk) ^ (bc & 7))];
                bf16x8 bf = __builtin_bit_cast(bf16x8, braw);
                acc[0][cf] = __builtin_amdgcn_mfma_f32_16x16x32_bf16(af0, bf, acc[0][cf], 0, 0, 0);
                acc[1][cf] = __builtin_amdgcn_mfma_f32_16x16x32_bf16(af1, bf, acc[1][cf], 0, 0, 0);
                acc[2][cf] = __builtin_amdgcn_mfma_f32_16x16x32_bf16(af2, bf, acc[2][cf], 0, 0, 0);
                acc[3][cf] = __builtin_amdgcn_mfma_f32_16x16x32_bf16(af3, bf, acc[3][cf], 0, 0, 0);
            }
        }
    }

    // Epilogue: lane-local cell update (gate g lives in acc[ar][g][r] for this lane's j)
    float4 xt0 = xtab[0 * HDIM + j];
    float4 xt1 = xtab[1 * HDIM + j];
    float4 xt2 = xtab[2 * HDIM + j];
    float4 xt3 = xtab[3 * HDIM + j];
    float fcwj = fcW[j];

#pragma unroll
    for (int ar = 0; ar < 4; ++ar) {
#pragma unroll
        for (int r = 0; r < 4; ++r) {
            const int n = mbw + ar * 16 + lk * 4 + r;   // D row = lk*4 + r
            float prev = (t == 0) ? 0.f : out[n * TSTEPS + t - 1];
            float fdv  = fd[n * TSTEPS + t];
            float gi = acc[ar][0][r] + xt0.x * prev + xt0.y * fdv + xt0.z;
            float gf = acc[ar][1][r] + xt1.x * prev + xt1.y * fdv + xt1.z;
            float gg = acc[ar][2][r] + xt2.x * prev + xt2.y * fdv + xt2.z;
            float go = acc[ar][3][r] + xt3.x * prev + xt3.y * fdv + xt3.z;
            float cold = c[n * HDIM + j];
            float cn = sigf(gf) * cold + sigf(gi) * tanhfast(gg);
            c[n * HDIM + j] = cn;
            float hn = sigf(go) * tanhfast(cn);
            hout[n * HDIM + j] = f2bf(hn);
            float pr = fcwj * hn;
            pr += __shfl_xor(pr, 1);
            pr += __shfl_xor(pr, 2);
            pr += __shfl_xor(pr, 4);
            pr += __shfl_xor(pr, 8);
            if (lr == 0) atomicAdd(&out[n * TSTEPS + t], pr);
        }
    }
}

extern "C" void kernel_launch(void* const* d_in, const int* in_sizes, int n_in,
                              void* d_out, int out_size, void* d_ws, size_t ws_size,
                              hipStream_t stream) {
    const float* fd  = (const float*)d_in[0];
    const float* h0  = (const float*)d_in[1];
    const float* c0  = (const float*)d_in[2];
    const float* Wih = (const float*)d_in[3];
    const float* Whh = (const float*)d_in[4];
    const float* bih = (const float*)d_in[5];
    const float* bhh = (const float*)d_in[6];
    const float* fcw = (const float*)d_in[7];
    const float* fcb = (const float*)d_in[8];
    float* out = (float*)d_out;

    char* ws = (char*)d_ws;
    u16*    Wb   = (u16*)(ws);
    u16*    hb0  = (u16*)(ws + 8388608);
    u16*    hb1  = (u16*)(ws + 12582912);
    float*  cbuf = (float*)(ws + 16777216);
    float4* xtab = (float4*)(ws + 25165824);

    k_prep_w    <<<dim3(4096), dim3(256), 0, stream>>>(Whh, Wb);
    k_prep_state<<<dim3(2048), dim3(256), 0, stream>>>(h0, c0, hb0, cbuf);
    k_prep_misc <<<dim3(16),   dim3(256), 0, stream>>>(Wih, bih, bhh, xtab);
    k_init_out  <<<dim3(256),  dim3(256), 0, stream>>>(out, fcb);

    for (int t = 0; t < TSTEPS; ++t) {
        const u16* hi = (t & 1) ? hb1 : hb0;
        u16*       ho = (t & 1) ? hb0 : hb1;
        k_step<<<dim3(32, 8), dim3(512), 0, stream>>>(hi, ho, cbuf, Wb, xtab, fd, fcw, out, t);
    }
}